// Round 1
// baseline (1155.582 us; speedup 1.0000x reference)
//
#include <hip/hip_runtime.h>
#include <hip/hip_bf16.h>
#include <math.h>

// Problem constants
#define TT 1024
#define DIM 1024
#define HH 8
#define QLR 768
#define KVLR 512
#define DNOPE 128
#define DROPE 64
#define DV 128
#define DK 192            // DNOPE + DROPE
#define HDK (HH*DK)       // 1536
#define HKV (HH*(DNOPE+DV)) // 2048

// ---------------------------------------------------------------------------
// Generic f32 GEMM: C = A(MxK) @ B(KxN), row-major, 64x64 tile, 4x4/thread.
// Requires M%64==0, N%64==0, K%16==0 (true for all call sites).
// ---------------------------------------------------------------------------
__global__ __launch_bounds__(256) void gemm64(
    const float* __restrict__ A, const float* __restrict__ B,
    float* __restrict__ C, int M, int N, int K)
{
    __shared__ float As[16][64];   // [k][m]
    __shared__ float Bs[16][64];   // [k][n]
    const int tid = threadIdx.x;
    const int bm = blockIdx.y * 64, bn = blockIdx.x * 64;
    const int tm = tid >> 4, tn = tid & 15;           // 16x16 thread grid
    const int ar = tid >> 2, ak = (tid & 3) * 4;      // A loader: 1 float4/thread
    const int bk = tid >> 4, bc = (tid & 15) * 4;     // B loader: 1 float4/thread

    float acc[4][4];
#pragma unroll
    for (int i = 0; i < 4; i++)
#pragma unroll
        for (int j = 0; j < 4; j++) acc[i][j] = 0.f;

    for (int k0 = 0; k0 < K; k0 += 16) {
        float4 av = *(const float4*)&A[(size_t)(bm + ar) * K + k0 + ak];
        float4 bv = *(const float4*)&B[(size_t)(k0 + bk) * N + bn + bc];
        __syncthreads();
        As[ak + 0][ar] = av.x; As[ak + 1][ar] = av.y;
        As[ak + 2][ar] = av.z; As[ak + 3][ar] = av.w;
        *(float4*)&Bs[bk][bc] = bv;
        __syncthreads();
#pragma unroll
        for (int kk = 0; kk < 16; kk++) {
            float4 a4 = *(const float4*)&As[kk][tm * 4];
            float4 b4 = *(const float4*)&Bs[kk][tn * 4];
            float aa[4] = {a4.x, a4.y, a4.z, a4.w};
            float bb[4] = {b4.x, b4.y, b4.z, b4.w};
#pragma unroll
            for (int i = 0; i < 4; i++)
#pragma unroll
                for (int j = 0; j < 4; j++) acc[i][j] += aa[i] * bb[j];
        }
    }
#pragma unroll
    for (int i = 0; i < 4; i++) {
        float4 v = make_float4(acc[i][0], acc[i][1], acc[i][2], acc[i][3]);
        *(float4*)&C[(size_t)(bm + tm * 4 + i) * N + bn + tn * 4] = v;
    }
}

// ---------------------------------------------------------------------------
// RMSNorm rows: out[t, :ncols] = in[t, :ncols] * rsqrt(mean(sq)+1e-5) * w
// ---------------------------------------------------------------------------
__global__ __launch_bounds__(256) void rmsnorm_rows(
    const float* __restrict__ in, int in_stride, const float* __restrict__ w,
    float* __restrict__ out, int out_stride, int ncols, float inv_n)
{
    const int t = blockIdx.x;
    const int tid = threadIdx.x;
    const float* row = in + (size_t)t * in_stride;
    float ss = 0.f;
    for (int c = tid; c < ncols; c += 256) { float v = row[c]; ss += v * v; }
#pragma unroll
    for (int m = 1; m < 64; m <<= 1) ss += __shfl_xor(ss, m);
    __shared__ float red[4];
    if ((tid & 63) == 0) red[tid >> 6] = ss;
    __syncthreads();
    float tot = red[0] + red[1] + red[2] + red[3];
    float scale = rsqrtf(tot * inv_n + 1e-5f);
    for (int c = tid; c < ncols; c += 256)
        out[(size_t)t * out_stride + c] = row[c] * scale * w[c];
}

// ---------------------------------------------------------------------------
// decay = sigmoid(gpre + bias[col])  (exp(log_sigmoid(z)) == sigmoid(z))
// ---------------------------------------------------------------------------
__global__ __launch_bounds__(256) void sigmoid_bias(
    float* __restrict__ g, const float* __restrict__ b, int ncols, int total)
{
    int i = blockIdx.x * 256 + threadIdx.x;
    if (i < total) {
        float z = g[i] + b[i % ncols];
        g[i] = 1.f / (1.f + expf(-z));
    }
}

// ---------------------------------------------------------------------------
// beta[t,h] = sigmoid(x[t,:] . wb[:,h])  — one wave per (t,h)
// ---------------------------------------------------------------------------
__global__ __launch_bounds__(256) void beta_kernel(
    const float* __restrict__ x, const float* __restrict__ wb,
    float* __restrict__ beta)
{
    const int lane = threadIdx.x & 63, wv = threadIdx.x >> 6;
    const int p = blockIdx.x * 4 + wv;        // p = t*8 + h
    const int t = p >> 3, h = p & 7;
    const float* xr = x + (size_t)t * DIM;
    float s = 0.f;
    for (int e = lane; e < DIM; e += 64) s += xr[e] * wb[e * HH + h];
#pragma unroll
    for (int m = 1; m < 64; m <<= 1) s += __shfl_xor(s, m);
    if (lane == 0) beta[p] = 1.f / (1.f + expf(-s));
}

// ---------------------------------------------------------------------------
// Prep: in-place l2norm(q)*DK^-0.5 on qn rows (192 per (t,h));
//       build k = [k_nope | k_pe], l2norm -> kn (T, H*192)
// One wave per (t,h).
// ---------------------------------------------------------------------------
__global__ __launch_bounds__(256) void prep_qk(
    float* __restrict__ q, const float* __restrict__ kvb,
    const float* __restrict__ kv_all, float* __restrict__ kn)
{
    const int lane = threadIdx.x & 63, wv = threadIdx.x >> 6;
    const int p = blockIdx.x * 4 + wv;
    const int t = p >> 3, h = p & 7;

    float* qrow = q + (size_t)t * HDK + h * DK;
    float q0 = qrow[lane], q1 = qrow[lane + 64], q2 = qrow[lane + 128];
    float ss = q0 * q0 + q1 * q1 + q2 * q2;
#pragma unroll
    for (int m = 1; m < 64; m <<= 1) ss += __shfl_xor(ss, m);
    float sc = rsqrtf(ss + 1e-6f) * 0.07216878364870323f;  // * DK^-0.5
    qrow[lane] = q0 * sc; qrow[lane + 64] = q1 * sc; qrow[lane + 128] = q2 * sc;

    const float* knope = kvb + (size_t)t * HKV + h * (DNOPE + DV);
    float k0 = knope[lane], k1 = knope[lane + 64];
    float k2 = kv_all[(size_t)t * (KVLR + DROPE) + KVLR + lane];
    float ks = k0 * k0 + k1 * k1 + k2 * k2;
#pragma unroll
    for (int m = 1; m < 64; m <<= 1) ks += __shfl_xor(ks, m);
    float kc = rsqrtf(ks + 1e-6f);
    float* kout = kn + (size_t)t * HDK + h * DK;
    kout[lane] = k0 * kc; kout[lane + 64] = k1 * kc; kout[lane + 128] = k2 * kc;
}

// ---------------------------------------------------------------------------
// KDA scan. Columns (h, v) are independent scans over a 192-dim state.
// 16 lanes per column, 12 state elems per lane, butterfly-reduce over 16.
// grid: 64 blocks (8 heads x 8 col-groups), block 256 = 4 waves = 16 cols.
// ---------------------------------------------------------------------------
__global__ __launch_bounds__(256) void kda_scan(
    const float* __restrict__ qn, const float* __restrict__ kn,
    const float* __restrict__ ag, const float* __restrict__ kvb,
    const float* __restrict__ beta, float* __restrict__ o)
{
    const int tid = threadIdx.x;
    const int wv = tid >> 6, lane = tid & 63;
    const int cw = lane >> 4, l = lane & 15;
    const int h = blockIdx.x >> 3, cg = blockIdx.x & 7;
    const int c = cg * 16 + wv * 4 + cw;     // v column 0..127

    const size_t base = (size_t)h * DK + l * 12;
    const float4* kp = (const float4*)(kn + base);
    const float4* ap = (const float4*)(ag + base);
    const float4* qp = (const float4*)(qn + base);
    const int s4 = HDK / 4;                   // 384 float4 per t

    float s[12];
#pragma unroll
    for (int j = 0; j < 12; j++) s[j] = 0.f;

    float4 kf0 = kp[0], kf1 = kp[1], kf2 = kp[2];
    float4 af0 = ap[0], af1 = ap[1], af2 = ap[2];
    float4 qf0 = qp[0], qf1 = qp[1], qf2 = qp[2];
    float vt = kvb[(size_t)h * (DNOPE + DV) + DNOPE + c];
    float bt = beta[h];

    for (int t = 0; t < TT; t++) {
        float kc[12], ac[12], qc[12];
        *(float4*)(kc) = kf0; *(float4*)(kc + 4) = kf1; *(float4*)(kc + 8) = kf2;
        *(float4*)(ac) = af0; *(float4*)(ac + 4) = af1; *(float4*)(ac + 8) = af2;
        *(float4*)(qc) = qf0; *(float4*)(qc + 4) = qf1; *(float4*)(qc + 8) = qf2;
        float vc = vt, bc = bt;

        // prefetch t+1 (clamped; redundant last-iter load is harmless)
        int tn = (t + 1 < TT) ? t + 1 : t;
        size_t off4 = (size_t)tn * s4;
        kf0 = kp[off4]; kf1 = kp[off4 + 1]; kf2 = kp[off4 + 2];
        af0 = ap[off4]; af1 = ap[off4 + 1]; af2 = ap[off4 + 2];
        qf0 = qp[off4]; qf1 = qp[off4 + 1]; qf2 = qp[off4 + 2];
        vt = kvb[(size_t)tn * HKV + h * (DNOPE + DV) + DNOPE + c];
        bt = beta[(size_t)tn * HH + h];

        // decay + k.S
        float a0 = 0.f, a1 = 0.f, a2 = 0.f, a3 = 0.f;
#pragma unroll
        for (int j = 0; j < 12; j += 4) {
            s[j]     *= ac[j];     a0 += kc[j]     * s[j];
            s[j + 1] *= ac[j + 1]; a1 += kc[j + 1] * s[j + 1];
            s[j + 2] *= ac[j + 2]; a2 += kc[j + 2] * s[j + 2];
            s[j + 3] *= ac[j + 3]; a3 += kc[j + 3] * s[j + 3];
        }
        float kv = (a0 + a1) + (a2 + a3);
        kv += __shfl_xor(kv, 1); kv += __shfl_xor(kv, 2);
        kv += __shfl_xor(kv, 4); kv += __shfl_xor(kv, 8);

        float u = bc * (vc - kv);

        // state update + q.S
        float o0 = 0.f, o1 = 0.f, o2 = 0.f, o3 = 0.f;
#pragma unroll
        for (int j = 0; j < 12; j += 4) {
            s[j]     += kc[j]     * u; o0 += qc[j]     * s[j];
            s[j + 1] += kc[j + 1] * u; o1 += qc[j + 1] * s[j + 1];
            s[j + 2] += kc[j + 2] * u; o2 += qc[j + 2] * s[j + 2];
            s[j + 3] += kc[j + 3] * u; o3 += qc[j + 3] * s[j + 3];
        }
        float ov = (o0 + o1) + (o2 + o3);
        ov += __shfl_xor(ov, 1); ov += __shfl_xor(ov, 2);
        ov += __shfl_xor(ov, 4); ov += __shfl_xor(ov, 8);

        if (l == 0) {
            if (isnan(ov)) ov = 0.f;
            else if (isinf(ov)) ov = ov > 0.f ? 1e4f : -1e4f;
            o[(size_t)t * (HH * DV) + h * DV + c] = ov;
        }
    }
}

// ---------------------------------------------------------------------------
extern "C" void kernel_launch(void* const* d_in, const int* in_sizes, int n_in,
                              void* d_out, int out_size, void* d_ws, size_t ws_size,
                              hipStream_t stream)
{
    const float* x         = (const float*)d_in[0];
    // d_in[1] = cos, d_in[2] = sin : unused by the reference
    const float* wq_a      = (const float*)d_in[3];
    const float* q_norm_w  = (const float*)d_in[4];
    const float* wq_b      = (const float*)d_in[5];
    const float* wkv_a     = (const float*)d_in[6];
    const float* kv_norm_w = (const float*)d_in[7];
    const float* wkv_b     = (const float*)d_in[8];
    const float* wg_w      = (const float*)d_in[9];
    const float* wg_b      = (const float*)d_in[10];
    const float* wb        = (const float*)d_in[11];
    const float* wo        = (const float*)d_in[12];
    float* out = (float*)d_out;

    float* ws = (float*)d_ws;
    float* xq     = ws;                    // T x 768
    float* xqn    = xq     + TT * QLR;     // T x 768
    float* kv_all = xqn    + TT * QLR;     // T x 576
    float* kvn    = kv_all + TT * (KVLR + DROPE); // T x 512
    float* ag     = kvn    + TT * KVLR;    // T x 1536 (decay, in-place sigmoid)
    float* betab  = ag     + TT * HDK;     // T x 8
    float* qn     = betab  + TT * HH;      // T x 1536 (in-place l2norm)
    float* kvb    = qn     + TT * HDK;     // T x 2048
    float* kn     = kvb    + TT * HKV;     // T x 1536
    float* ob     = kn     + TT * HDK;     // T x 1024

    dim3 blk(256);

    // x projections
    gemm64<<<dim3(QLR / 64, TT / 64), blk, 0, stream>>>(x, wq_a, xq, TT, QLR, DIM);
    gemm64<<<dim3((KVLR + DROPE) / 64, TT / 64), blk, 0, stream>>>(x, wkv_a, kv_all, TT, KVLR + DROPE, DIM);
    gemm64<<<dim3(HDK / 64, TT / 64), blk, 0, stream>>>(x, wg_w, ag, TT, HDK, DIM);

    // norms
    rmsnorm_rows<<<TT, blk, 0, stream>>>(xq, QLR, q_norm_w, xqn, QLR, QLR, 1.f / QLR);
    rmsnorm_rows<<<TT, blk, 0, stream>>>(kv_all, KVLR + DROPE, kv_norm_w, kvn, KVLR, KVLR, 1.f / KVLR);

    // low-rank expansions
    gemm64<<<dim3(HDK / 64, TT / 64), blk, 0, stream>>>(xqn, wq_b, qn, TT, HDK, QLR);
    gemm64<<<dim3(HKV / 64, TT / 64), blk, 0, stream>>>(kvn, wkv_b, kvb, TT, HKV, KVLR);

    // gates
    sigmoid_bias<<<(TT * HDK + 255) / 256, blk, 0, stream>>>(ag, wg_b, HDK, TT * HDK);
    beta_kernel<<<TT * HH / 4, blk, 0, stream>>>(x, wb, betab);

    // l2norm q, build+l2norm k
    prep_qk<<<TT * HH / 4, blk, 0, stream>>>(qn, kvb, kv_all, kn);

    // sequential gated delta-rule scan (per-column parallel)
    kda_scan<<<64, blk, 0, stream>>>(qn, kn, ag, kvb, betab, ob);

    // output projection
    gemm64<<<dim3(DIM / 64, TT / 64), blk, 0, stream>>>(ob, wo, out, TT, DIM, DIM);
}

// Round 2
// 780.417 us; speedup vs baseline: 1.4807x; 1.4807x over previous
//
#include <hip/hip_runtime.h>
#include <hip/hip_bf16.h>
#include <math.h>

// Problem constants
#define TT 1024
#define DIM 1024
#define HH 8
#define QLR 768
#define KVLR 512
#define DNOPE 128
#define DROPE 64
#define DV 128
#define DK 192            // DNOPE + DROPE
#define HDK (HH*DK)       // 1536
#define HKV (HH*(DNOPE+DV)) // 2048

// ---------------------------------------------------------------------------
// Generic f32 GEMM: C = A(MxK) @ B(KxN), row-major, 64x64 tile, 4x4/thread.
// ---------------------------------------------------------------------------
__global__ __launch_bounds__(256) void gemm64(
    const float* __restrict__ A, const float* __restrict__ B,
    float* __restrict__ C, int M, int N, int K)
{
    __shared__ float As[16][64];   // [k][m]
    __shared__ float Bs[16][64];   // [k][n]
    const int tid = threadIdx.x;
    const int bm = blockIdx.y * 64, bn = blockIdx.x * 64;
    const int tm = tid >> 4, tn = tid & 15;
    const int ar = tid >> 2, ak = (tid & 3) * 4;
    const int bk = tid >> 4, bc = (tid & 15) * 4;

    float acc[4][4];
#pragma unroll
    for (int i = 0; i < 4; i++)
#pragma unroll
        for (int j = 0; j < 4; j++) acc[i][j] = 0.f;

    for (int k0 = 0; k0 < K; k0 += 16) {
        float4 av = *(const float4*)&A[(size_t)(bm + ar) * K + k0 + ak];
        float4 bv = *(const float4*)&B[(size_t)(k0 + bk) * N + bn + bc];
        __syncthreads();
        As[ak + 0][ar] = av.x; As[ak + 1][ar] = av.y;
        As[ak + 2][ar] = av.z; As[ak + 3][ar] = av.w;
        *(float4*)&Bs[bk][bc] = bv;
        __syncthreads();
#pragma unroll
        for (int kk = 0; kk < 16; kk++) {
            float4 a4 = *(const float4*)&As[kk][tm * 4];
            float4 b4 = *(const float4*)&Bs[kk][tn * 4];
            float aa[4] = {a4.x, a4.y, a4.z, a4.w};
            float bb[4] = {b4.x, b4.y, b4.z, b4.w};
#pragma unroll
            for (int i = 0; i < 4; i++)
#pragma unroll
                for (int j = 0; j < 4; j++) acc[i][j] += aa[i] * bb[j];
        }
    }
#pragma unroll
    for (int i = 0; i < 4; i++) {
        float4 v = make_float4(acc[i][0], acc[i][1], acc[i][2], acc[i][3]);
        *(float4*)&C[(size_t)(bm + tm * 4 + i) * N + bn + tn * 4] = v;
    }
}

// ---------------------------------------------------------------------------
__global__ __launch_bounds__(256) void rmsnorm_rows(
    const float* __restrict__ in, int in_stride, const float* __restrict__ w,
    float* __restrict__ out, int out_stride, int ncols, float inv_n)
{
    const int t = blockIdx.x;
    const int tid = threadIdx.x;
    const float* row = in + (size_t)t * in_stride;
    float ss = 0.f;
    for (int c = tid; c < ncols; c += 256) { float v = row[c]; ss += v * v; }
#pragma unroll
    for (int m = 1; m < 64; m <<= 1) ss += __shfl_xor(ss, m);
    __shared__ float red[4];
    if ((tid & 63) == 0) red[tid >> 6] = ss;
    __syncthreads();
    float tot = red[0] + red[1] + red[2] + red[3];
    float scale = rsqrtf(tot * inv_n + 1e-5f);
    for (int c = tid; c < ncols; c += 256)
        out[(size_t)t * out_stride + c] = row[c] * scale * w[c];
}

// ---------------------------------------------------------------------------
__global__ __launch_bounds__(256) void sigmoid_bias(
    float* __restrict__ g, const float* __restrict__ b, int ncols, int total)
{
    int i = blockIdx.x * 256 + threadIdx.x;
    if (i < total) {
        float z = g[i] + b[i % ncols];
        g[i] = 1.f / (1.f + expf(-z));
    }
}

// ---------------------------------------------------------------------------
__global__ __launch_bounds__(256) void beta_kernel(
    const float* __restrict__ x, const float* __restrict__ wb,
    float* __restrict__ beta)
{
    const int lane = threadIdx.x & 63, wv = threadIdx.x >> 6;
    const int p = blockIdx.x * 4 + wv;        // p = t*8 + h
    const int t = p >> 3, h = p & 7;
    const float* xr = x + (size_t)t * DIM;
    float s = 0.f;
    for (int e = lane; e < DIM; e += 64) s += xr[e] * wb[e * HH + h];
#pragma unroll
    for (int m = 1; m < 64; m <<= 1) s += __shfl_xor(s, m);
    if (lane == 0) beta[p] = 1.f / (1.f + expf(-s));
}

// ---------------------------------------------------------------------------
__global__ __launch_bounds__(256) void prep_qk(
    float* __restrict__ q, const float* __restrict__ kvb,
    const float* __restrict__ kv_all, float* __restrict__ kn)
{
    const int lane = threadIdx.x & 63, wv = threadIdx.x >> 6;
    const int p = blockIdx.x * 4 + wv;
    const int t = p >> 3, h = p & 7;

    float* qrow = q + (size_t)t * HDK + h * DK;
    float q0 = qrow[lane], q1 = qrow[lane + 64], q2 = qrow[lane + 128];
    float ss = q0 * q0 + q1 * q1 + q2 * q2;
#pragma unroll
    for (int m = 1; m < 64; m <<= 1) ss += __shfl_xor(ss, m);
    float sc = rsqrtf(ss + 1e-6f) * 0.07216878364870323f;  // * DK^-0.5
    qrow[lane] = q0 * sc; qrow[lane + 64] = q1 * sc; qrow[lane + 128] = q2 * sc;

    const float* knope = kvb + (size_t)t * HKV + h * (DNOPE + DV);
    float k0 = knope[lane], k1 = knope[lane + 64];
    float k2 = kv_all[(size_t)t * (KVLR + DROPE) + KVLR + lane];
    float ks = k0 * k0 + k1 * k1 + k2 * k2;
#pragma unroll
    for (int m = 1; m < 64; m <<= 1) ks += __shfl_xor(ks, m);
    float kc = rsqrtf(ks + 1e-6f);
    float* kout = kn + (size_t)t * HDK + h * DK;
    kout[lane] = k0 * kc; kout[lane + 64] = k1 * kc; kout[lane + 128] = k2 * kc;
}

// ---------------------------------------------------------------------------
// 32-lane sum reduction: 4 DPP stages (VALU pipe) + 1 ds_swizzle xor16.
// quad_perm xor1 = 0xB1, quad_perm xor2 = 0x4E,
// row_half_mirror = 0x141, row_mirror = 0x140.
// ---------------------------------------------------------------------------
__device__ __forceinline__ float red32(float x) {
    x += __int_as_float(__builtin_amdgcn_update_dpp(0, __float_as_int(x), 0xB1, 0xF, 0xF, false));
    x += __int_as_float(__builtin_amdgcn_update_dpp(0, __float_as_int(x), 0x4E, 0xF, 0xF, false));
    x += __int_as_float(__builtin_amdgcn_update_dpp(0, __float_as_int(x), 0x141, 0xF, 0xF, false));
    x += __int_as_float(__builtin_amdgcn_update_dpp(0, __float_as_int(x), 0x140, 0xF, 0xF, false));
    x += __int_as_float(__builtin_amdgcn_ds_swizzle(__float_as_int(x), 0x401F));
    return x;
}

// ---------------------------------------------------------------------------
// KDA scan, pipelined form. 32 lanes per (h,v)-column, 6 state elems/lane.
// Recurrences (per column c, state s in R^192):
//   s~_t = a_t o (s~_{t-1} + u_{t-1} k_{t-1})
//   u_t  = b_t (v_t - k_t . s~_t)
//   o_t  = q_t . s~_t + u_t (q_t . k_t)
// Only ONE reduction (k.s~) feeds the scalar chain; q-dots are off the
// critical path. Ping-pong register buffers, prefetch t+1 during step t.
// grid: 128 blocks x 256 (8 heads x 16 col-groups, 8 cols/block).
// ---------------------------------------------------------------------------
__global__ __launch_bounds__(256) void kda_scan2(
    const float* __restrict__ qn, const float* __restrict__ kn,
    const float* __restrict__ ag, const float* __restrict__ kvb,
    const float* __restrict__ beta, float* __restrict__ o)
{
    const int tid = threadIdx.x;
    const int wv = tid >> 6, lane = tid & 63;
    const int half = lane >> 5, l = lane & 31;
    const int h = blockIdx.x >> 4, cg = blockIdx.x & 15;
    const int c = cg * 8 + wv * 2 + half;     // v column 0..127

    // lane owns elems [l*4 .. l*4+3] and [128 + l*2, 128 + l*2 + 1] of the
    // head's 192-dim k-slice (alignment: 16B and 8B resp.)
    const size_t eb = (size_t)h * DK;
    const float* kp4 = kn + eb + l * 4;
    const float* kp2 = kn + eb + 128 + l * 2;
    const float* ap4 = ag + eb + l * 4;
    const float* ap2 = ag + eb + 128 + l * 2;
    const float* qp4 = qn + eb + l * 4;
    const float* qp2 = qn + eb + 128 + l * 2;
    const float* vp  = kvb + (size_t)h * (DNOPE + DV) + DNOPE + c;
    const float* bp  = beta + h;
    float* op = o + (size_t)h * DV + c;

    float sd[6];
#pragma unroll
    for (int j = 0; j < 6; j++) sd[j] = 0.f;

    float kA[6], aA[6], qA[6], kB[6], aB[6], qB[6];
    float vA, bA, vB, bB;

    // load t=0 into A; kB=0 acts as k_{-1}
    {
        float4 f; float2 g;
        f = *(const float4*)kp4; kA[0]=f.x; kA[1]=f.y; kA[2]=f.z; kA[3]=f.w;
        g = *(const float2*)kp2; kA[4]=g.x; kA[5]=g.y;
        f = *(const float4*)ap4; aA[0]=f.x; aA[1]=f.y; aA[2]=f.z; aA[3]=f.w;
        g = *(const float2*)ap2; aA[4]=g.x; aA[5]=g.y;
        f = *(const float4*)qp4; qA[0]=f.x; qA[1]=f.y; qA[2]=f.z; qA[3]=f.w;
        g = *(const float2*)qp2; qA[4]=g.x; qA[5]=g.y;
        vA = *vp; bA = *bp;
    }
#pragma unroll
    for (int j = 0; j < 6; j++) { kB[j] = 0.f; aB[j] = 0.f; qB[j] = 0.f; }
    vB = 0.f; bB = 0.f;

    float u_prev = 0.f;

    auto step = [&](float (&kC)[6], float (&aC)[6], float (&qC)[6],
                    float& vC, float& bC,
                    float (&kN)[6], float (&aN)[6], float (&qN)[6],
                    float& vN, float& bN, int t) {
        // state advance: sd = a_t o (sd + u_prev * k_{t-1});  k_{t-1} == kN
#pragma unroll
        for (int j = 0; j < 6; j++) {
            float tmp = fmaf(u_prev, kN[j], sd[j]);
            sd[j] = aC[j] * tmp;
        }
        // prefetch t+1 into N (kN consumed above; safe to overwrite)
        int tn = t + 1; if (tn > TT - 1) tn = TT - 1;
        {
            size_t o4 = (size_t)tn * HDK;
            float4 f; float2 g;
            f = *(const float4*)(kp4 + o4); kN[0]=f.x; kN[1]=f.y; kN[2]=f.z; kN[3]=f.w;
            g = *(const float2*)(kp2 + o4); kN[4]=g.x; kN[5]=g.y;
            f = *(const float4*)(ap4 + o4); aN[0]=f.x; aN[1]=f.y; aN[2]=f.z; aN[3]=f.w;
            g = *(const float2*)(ap2 + o4); aN[4]=g.x; aN[5]=g.y;
            f = *(const float4*)(qp4 + o4); qN[0]=f.x; qN[1]=f.y; qN[2]=f.z; qN[3]=f.w;
            g = *(const float2*)(qp2 + o4); qN[4]=g.x; qN[5]=g.y;
            vN = vp[(size_t)tn * HKV];
            bN = bp[(size_t)tn * HH];
        }
        // dots
        float pk = 0.f, pq = 0.f, pqk = 0.f;
#pragma unroll
        for (int j = 0; j < 6; j++) {
            pk  += kC[j] * sd[j];
            pq  += qC[j] * sd[j];
            pqk += qC[j] * kC[j];
        }
        float dK = red32(pk);                 // on critical path
        float u  = bC * (vC - dK);
        float dQ  = red32(pq);                // off critical path
        float dQK = red32(pqk);
        float ov = fmaf(u, dQK, dQ);
        if (isnan(ov)) ov = 0.f;
        else if (isinf(ov)) ov = ov > 0.f ? 1e4f : -1e4f;
        if (l == 0) op[(size_t)t * (HH * DV)] = ov;
        u_prev = u;
    };

    for (int t = 0; t < TT; t += 2) {
        step(kA, aA, qA, vA, bA, kB, aB, qB, vB, bB, t);
        step(kB, aB, qB, vB, bB, kA, aA, qA, vA, bA, t + 1);
    }
}

// ---------------------------------------------------------------------------
extern "C" void kernel_launch(void* const* d_in, const int* in_sizes, int n_in,
                              void* d_out, int out_size, void* d_ws, size_t ws_size,
                              hipStream_t stream)
{
    const float* x         = (const float*)d_in[0];
    // d_in[1] = cos, d_in[2] = sin : unused by the reference
    const float* wq_a      = (const float*)d_in[3];
    const float* q_norm_w  = (const float*)d_in[4];
    const float* wq_b      = (const float*)d_in[5];
    const float* wkv_a     = (const float*)d_in[6];
    const float* kv_norm_w = (const float*)d_in[7];
    const float* wkv_b     = (const float*)d_in[8];
    const float* wg_w      = (const float*)d_in[9];
    const float* wg_b      = (const float*)d_in[10];
    const float* wb        = (const float*)d_in[11];
    const float* wo        = (const float*)d_in[12];
    float* out = (float*)d_out;

    float* ws = (float*)d_ws;
    float* xq     = ws;                    // T x 768
    float* xqn    = xq     + TT * QLR;     // T x 768
    float* kv_all = xqn    + TT * QLR;     // T x 576
    float* kvn    = kv_all + TT * (KVLR + DROPE); // T x 512
    float* ag     = kvn    + TT * KVLR;    // T x 1536 (decay, in-place sigmoid)
    float* betab  = ag     + TT * HDK;     // T x 8
    float* qn     = betab  + TT * HH;      // T x 1536 (in-place l2norm)
    float* kvb    = qn     + TT * HDK;     // T x 2048
    float* kn     = kvb    + TT * HKV;     // T x 1536
    float* ob     = kn     + TT * HDK;     // T x 1024

    dim3 blk(256);

    // x projections
    gemm64<<<dim3(QLR / 64, TT / 64), blk, 0, stream>>>(x, wq_a, xq, TT, QLR, DIM);
    gemm64<<<dim3((KVLR + DROPE) / 64, TT / 64), blk, 0, stream>>>(x, wkv_a, kv_all, TT, KVLR + DROPE, DIM);
    gemm64<<<dim3(HDK / 64, TT / 64), blk, 0, stream>>>(x, wg_w, ag, TT, HDK, DIM);

    // norms
    rmsnorm_rows<<<TT, blk, 0, stream>>>(xq, QLR, q_norm_w, xqn, QLR, QLR, 1.f / QLR);
    rmsnorm_rows<<<TT, blk, 0, stream>>>(kv_all, KVLR + DROPE, kv_norm_w, kvn, KVLR, KVLR, 1.f / KVLR);

    // low-rank expansions
    gemm64<<<dim3(HDK / 64, TT / 64), blk, 0, stream>>>(xqn, wq_b, qn, TT, HDK, QLR);
    gemm64<<<dim3(HKV / 64, TT / 64), blk, 0, stream>>>(kvn, wkv_b, kvb, TT, HKV, KVLR);

    // gates
    sigmoid_bias<<<(TT * HDK + 255) / 256, blk, 0, stream>>>(ag, wg_b, HDK, TT * HDK);
    beta_kernel<<<TT * HH / 4, blk, 0, stream>>>(x, wb, betab);

    // l2norm q, build+l2norm k
    prep_qk<<<TT * HH / 4, blk, 0, stream>>>(qn, kvb, kv_all, kn);

    // pipelined gated delta-rule scan
    kda_scan2<<<128, blk, 0, stream>>>(qn, kn, ag, kvb, betab, ob);

    // output projection
    gemm64<<<dim3(DIM / 64, TT / 64), blk, 0, stream>>>(ob, wo, out, TT, DIM, DIM);
}